// Round 12
// baseline (113.773 us; speedup 1.0000x reference)
//
#include <hip/hip_runtime.h>
#include <hip/hip_bf16.h>
#include <hip/hip_fp8.h>

#define SIZE 6144
#define DDIM 2048
#define BHALF 2048
#define BIJ 4096
#define NT 48   // 6144 / 128 tiles per dim

typedef __attribute__((ext_vector_type(4))) float f32x4;
typedef __attribute__((ext_vector_type(4))) int i32x4;
typedef __attribute__((ext_vector_type(8))) int i32x8;

__device__ __forceinline__ float block_reduce_sum(float v, float* red) {
    #pragma unroll
    for (int off = 32; off; off >>= 1) v += __shfl_xor(v, off, 64);
    int lane = threadIdx.x & 63, wid = threadIdx.x >> 6;
    if (lane == 0) red[wid] = v;
    __syncthreads();
    float t = red[0] + red[1] + red[2] + red[3];
    __syncthreads();
    return t;
}

// One block (256 thr) per row: L2-normalize in fp32, write fp8-e4m3 of
// (z * 64)  (MX scale 2^-6 per operand dequants to z exactly), and
// dii[r] = ||z_q||^2 from the SAME quantized values so the diagonal exp
// term cancels consistently. Blocks 0..47 also zero the S accumulator.
__global__ __launch_bounds__(256) void normalize_kernel(
    const float* __restrict__ ei, const float* __restrict__ ej,
    const float* __restrict__ ek,
    unsigned char* __restrict__ zb, float* __restrict__ dii,
    float* __restrict__ S)
{
    __shared__ float red[4];
    int r = blockIdx.x;
    if (r < 48) S[r * 256 + threadIdx.x] = 0.f;   // 48*256 = 2*SIZE
    const float* src = (r < BHALF)   ? (ei + (size_t)r * DDIM)
                     : (r < 2*BHALF) ? (ej + (size_t)(r - BHALF) * DDIM)
                                     : (ek + (size_t)(r - 2*BHALF) * DDIM);
    int t = threadIdx.x;
    float4 v0 = ((const float4*)src)[t*2];
    float4 v1 = ((const float4*)src)[t*2 + 1];
    float ss = v0.x*v0.x + v0.y*v0.y + v0.z*v0.z + v0.w*v0.w
             + v1.x*v1.x + v1.y*v1.y + v1.z*v1.z + v1.w*v1.w;
    float tot = block_reduce_sum(ss, red);
    float scale = 64.0f / fmaxf(sqrtf(tot), 1e-12f);   // z * 64

    float xs[8] = {v0.x, v0.y, v0.z, v0.w, v1.x, v1.y, v1.z, v1.w};
    unsigned char u[8];
    float d = 0.f;
    #pragma unroll
    for (int j = 0; j < 8; ++j) {
        __hip_fp8_e4m3 h(xs[j] * scale);
        u[j] = h.__x;
        float f = (float)h;
        d += f * f;
    }
    *(unsigned long long*)&zb[(size_t)r * DDIM + t*8] = *(unsigned long long*)u;
    float dtot = block_reduce_sum(d, red);
    if (t == 0) dii[r] = dtot * (1.0f / 4096.0f);
}

// Symmetric simexp, MX-fp8, depth-2 ring-3 pipeline:
//   512 threads (8 waves, 2/SIMD at 1 block/CU), 128x128 tile, BK=128.
//   LDS ring of 3 tile-buffers (96 KiB). Iter t:
//     vmcnt(4)  -> retires STAGE(t)'s 4 loads (leaves STAGE(t+1) in flight)
//     s_barrier -> all waves' tile-t data in LDS; all reads of slot (t-1)%3 done
//     STAGE(t+2) into slot (t+2)%3 (the slot freed at t-1)
//     ds_read + 8 MFMA on slot t%3
//   Staged tiles get ~2 full iterations of flight time (counted vmcnt never
//   drains to 0 in steady state). Tail: vmcnt(0) at t=15; stages stop at t=13.
// XOR-swizzle within each row's 128B granule (coalescing-preserving,
// conflict-free reads); XCD-aware triangular decode.
__global__ __launch_bounds__(512) void simexp_kernel(
    const unsigned char* __restrict__ zb, float* __restrict__ S)
{
    __shared__ unsigned char As[3][128 * 128];   // 3 x 16 KiB
    __shared__ unsigned char Bs[3][128 * 128];   // 3 x 16 KiB

    // XCD-aware triangular decode (1176 = 24 row-pairs x 49 jobs; 8 XCDs x 147)
    const int x  = blockIdx.x & 7;
    const int j  = blockIdx.x >> 3;
    const int pi = j / 49;
    const int jj = j % 49;
    const int p  = 3 * x + pi;
    int rt, ct;
    if (jj < 48 - p) { rt = p;      ct = p + jj; }
    else             { rt = 47 - p; ct = rt + (jj - (48 - p)); }

    const int tid  = threadIdx.x;
    const int lane = tid & 63;
    const int w    = tid >> 6;       // wave 0..7
    const int wr   = w >> 1;         // 0..3: 32-row band
    const int wc   = w & 1;          // 0..1: 64-col band
    const int rowA0 = rt * 128, colB0 = ct * 128;

    const int rowc = lane >> 3;                      // row within 8-row chunk
    const int ksw  = ((lane & 7) ^ rowc) * 16;       // swizzled 16B chunk (bytes)

    f32x4 acc[2][4] = {};

    const int lr = lane & 15;
    const int l4 = lane >> 4;          // 0..3
    const int r7 = lr & 7;

    // staging duty: wave w covers rows [w*16, w*16+16) of A and B
#define STAGE(slot, kb) do {                                                 \
    _Pragma("unroll")                                                        \
    for (int it = 0; it < 2; ++it) {                                         \
        int rchunk = w * 16 + it * 8;                                        \
        const unsigned char* ga =                                            \
            zb + (size_t)(rowA0 + rchunk + rowc) * DDIM + (kb) + ksw;        \
        __builtin_amdgcn_global_load_lds(                                    \
            (const __attribute__((address_space(1))) void*)ga,               \
            (__attribute__((address_space(3))) void*)&As[slot][rchunk * 128],\
            16, 0, 0);                                                       \
        const unsigned char* gb =                                            \
            zb + (size_t)(colB0 + rchunk + rowc) * DDIM + (kb) + ksw;        \
        __builtin_amdgcn_global_load_lds(                                    \
            (const __attribute__((address_space(1))) void*)gb,               \
            (__attribute__((address_space(3))) void*)&Bs[slot][rchunk * 128],\
            16, 0, 0);                                                       \
    }                                                                        \
} while (0)

    // prologue: tiles 0 and 1 in flight (8 loads/wave outstanding)
    STAGE(0, 0);
    STAGE(1, 128);

    for (int t = 0; t < 16; ++t) {
        const int cur = t % 3;
        if (t < 15) { asm volatile("s_waitcnt vmcnt(4)" ::: "memory"); }
        else        { asm volatile("s_waitcnt vmcnt(0)" ::: "memory"); }
        __builtin_amdgcn_s_barrier();
        if (t <= 13) STAGE((t + 2) % 3, (t + 2) * 128);

        // A fragments: lane covers k-bytes [l4*32, l4*32+32) of its row,
        // i.e. chunks {2*l4, 2*l4+1}, stored at slots (chunk ^ (row&7)).
        i32x8 af[2];
        #pragma unroll
        for (int mi = 0; mi < 2; ++mi) {
            const int base = (wr*32 + mi*16 + lr) * 128;
            i32x4 lo = *(const i32x4*)&As[cur][base + (((2*l4)     ^ r7) << 4)];
            i32x4 hi = *(const i32x4*)&As[cur][base + (((2*l4 + 1) ^ r7) << 4)];
            af[mi] = __builtin_shufflevector(lo, hi, 0, 1, 2, 3, 4, 5, 6, 7);
        }
        __builtin_amdgcn_s_setprio(1);
        #pragma unroll
        for (int ni = 0; ni < 4; ++ni) {
            const int base = (wc*64 + ni*16 + lr) * 128;
            i32x4 lo = *(const i32x4*)&Bs[cur][base + (((2*l4)     ^ r7) << 4)];
            i32x4 hi = *(const i32x4*)&Bs[cur][base + (((2*l4 + 1) ^ r7) << 4)];
            i32x8 bf = __builtin_shufflevector(lo, hi, 0, 1, 2, 3, 4, 5, 6, 7);
            #pragma unroll
            for (int mi = 0; mi < 2; ++mi)
                acc[mi][ni] = __builtin_amdgcn_mfma_scale_f32_16x16x128_f8f6f4(
                    af[mi], bf, acc[mi][ni], 0, 0,
                    0, 0x79797979, 0, 0x79797979);
        }
        __builtin_amdgcn_s_setprio(0);
    }

    // exp in-register (reused for both row- and col-sums)
    #pragma unroll
    for (int mi = 0; mi < 2; ++mi)
        #pragma unroll
        for (int ni = 0; ni < 4; ++ni)
            #pragma unroll
            for (int q = 0; q < 4; ++q)
                acc[mi][ni][q] = __expf(10.0f * acc[mi][ni][q]);

    // ---- row-sums: D row = wr*32 + mi*16 + (lane>>4)*4 + q, col = wc*64 + ni*16 + (lane&15)
    {
        float rs[2][4];
        #pragma unroll
        for (int mi = 0; mi < 2; ++mi)
            #pragma unroll
            for (int q = 0; q < 4; ++q) {
                float s = 0.f;
                #pragma unroll
                for (int ni = 0; ni < 4; ++ni) s += acc[mi][ni][q];
                rs[mi][q] = s;
            }
        #pragma unroll
        for (int off = 1; off < 16; off <<= 1)
            #pragma unroll
            for (int mi = 0; mi < 2; ++mi)
                #pragma unroll
                for (int q = 0; q < 4; ++q)
                    rs[mi][q] += __shfl_xor(rs[mi][q], off, 64);

        if ((lane & 15) == 0) {
            float* St = S + ((ct < BIJ / 128) ? 0 : SIZE);
            int rq = l4 * 4;
            #pragma unroll
            for (int mi = 0; mi < 2; ++mi)
                #pragma unroll
                for (int q = 0; q < 4; ++q)
                    atomicAdd(&St[rowA0 + wr*32 + mi*16 + rq + q], rs[mi][q]);
        }
    }

    // ---- col-sums (transpose contribution), off-diagonal tiles only
    if (rt != ct) {
        float cs[4];
        #pragma unroll
        for (int ni = 0; ni < 4; ++ni) {
            float s = 0.f;
            #pragma unroll
            for (int mi = 0; mi < 2; ++mi)
                #pragma unroll
                for (int q = 0; q < 4; ++q) s += acc[mi][ni][q];
            cs[ni] = s;
        }
        #pragma unroll
        for (int off = 16; off < 64; off <<= 1)
            #pragma unroll
            for (int ni = 0; ni < 4; ++ni)
                cs[ni] += __shfl_xor(cs[ni], off, 64);

        if (lane < 16) {
            float* St = S + ((rt < BIJ / 128) ? 0 : SIZE);
            #pragma unroll
            for (int ni = 0; ni < 4; ++ni)
                atomicAdd(&St[colB0 + wc*64 + ni*16 + lane], cs[ni]);
        }
    }
}

// Single block: per-row loss terms, total, write scalar.
__global__ __launch_bounds__(256) void loss_kernel(
    const float* __restrict__ S, const float* __restrict__ dii,
    float* __restrict__ out)
{
    __shared__ float red[4];
    float local = 0.f;
    const float c1 = logf((float)(BIJ - 1));
    const float c2 = logf((float)(BHALF - 1));
    for (int r = threadIdx.x; r < SIZE; r += 256) {
        float s1 = S[r], s2 = S[SIZE + r];
        float eii = __expf(10.0f * dii[r]);
        float denom = s1 + s2 - eii;
        float num, c;
        if (r < BIJ) { num = s1 - eii; c = c1; }
        else         { num = s2 - eii; c = c2; }
        local += logf(denom) - logf(num) + c;
    }
    float tot = block_reduce_sum(local, red);
    if (threadIdx.x == 0) out[0] = tot / (float)SIZE;
}

extern "C" void kernel_launch(void* const* d_in, const int* in_sizes, int n_in,
                              void* d_out, int out_size, void* d_ws, size_t ws_size,
                              hipStream_t stream) {
    const float* ei = (const float*)d_in[0];
    const float* ej = (const float*)d_in[1];
    const float* ek = (const float*)d_in[2];
    float* out = (float*)d_out;

    char* ws = (char*)d_ws;
    unsigned char* zb = (unsigned char*)ws;                      // 6144*2048*1 = 12582912 B
    float* dii = (float*)(ws + 12582912);                        // 24576 B
    float* S   = (float*)(ws + 12582912 + 24576);                // 2*6144*4 = 49152 B

    normalize_kernel<<<dim3(SIZE), dim3(256), 0, stream>>>(ei, ej, ek, zb, dii, S);
    simexp_kernel<<<dim3(NT * (NT + 1) / 2), dim3(512), 0, stream>>>(zb, S);
    loss_kernel<<<dim3(1), dim3(256), 0, stream>>>(S, dii, out);
}